// Round 3
// baseline (128.868 us; speedup 1.0000x reference)
//
#include <hip/hip_runtime.h>

using u16 = unsigned short;
using u32 = unsigned int;
typedef float v2f   __attribute__((ext_vector_type(2)));
typedef float f32x4 __attribute__((ext_vector_type(4)));
typedef short s16x8 __attribute__((ext_vector_type(8)));

union FragU { u32 d[4]; s16x8 s; uint4 q; };

// Single-instruction RNE pack of two f32 -> packed bf16 {lo=a, hi=b}.
__device__ __forceinline__ u32 cvt_pk_bf16(float a, float b) {
    u32 r;
    asm("v_cvt_pk_bf16_f32 %0, %1, %2" : "=v"(r) : "v"(a), "v"(b));
    return r;
}
// weight split: hi = truncated bf16 pair, lo = RNE bf16 of exact residual
__device__ __forceinline__ void split2(float w0, float w1, u32& hi, u32& lo) {
    u32 u0 = __float_as_uint(w0), u1 = __float_as_uint(w1);
    hi = (u0 >> 16) | (u1 & 0xFFFF0000u);
    float r0 = w0 - __uint_as_float(u0 & 0xFFFF0000u);
    float r1 = w1 - __uint_as_float(u1 & 0xFFFF0000u);
    lo = cvt_pk_bf16(r0, r1);
}
__device__ __forceinline__ u32 bp(int ib, u32 v) {           // full-exec crossbar pull
    return (u32)__builtin_amdgcn_ds_bpermute(ib, (int)v);
}
__device__ __forceinline__ v2f pkfma(v2f a, v2f b, v2f c) { return __builtin_elementwise_fma(a, b, c); }
__device__ __forceinline__ v2f s2v(float x) { return (v2f){x, x}; }
__device__ __forceinline__ f32x4 tov(float4 v) { return (f32x4){v.x, v.y, v.z, v.w}; }
#define MFMA16 __builtin_amdgcn_mfma_f32_16x16x32_bf16

// Thread = TWO batch rows (rowA = wavebase+lane, rowB = wavebase+64+lane);
// wave = 128 rows = 8 MFMA tiles -> 8 independent tile chains + 2 independent
// quantum chains per wave (latency hiding via ILP, not just TLP).
// Inter-layer transposes via ds_bpermute (register-resident, no cross-tile deps).
__global__ void __launch_bounds__(256) qae_bperm(
    const float* __restrict__ x,  const float* __restrict__ qw,
    const float* __restrict__ W1, const float* __restrict__ b1,
    const float* __restrict__ W2, const float* __restrict__ b2,
    const float* __restrict__ W3, const float* __restrict__ b3,
    float* __restrict__ out, int n)
{
    int tid  = threadIdx.x;
    int lane = tid & 63;
    int wid  = tid >> 6;
    int vn   = lane & 15, vq = lane >> 4;
    int wavebase = blockIdx.x * 512 + wid * 128;     // wave's first global row

    __shared__ uint4 shfrag[8][64];      // 8 KB: A1h,A1l,A2ah,A2al,A2bh,A2bl,A3h,A3l

    // ---- x loads first (HBM latency); 2 rows per thread ----
    int r0 = wavebase + lane;
    int rA = r0 < n ? r0 : n - 1;
    int r1i = r0 + 64;
    int rB = r1i < n ? r1i : n - 1;
    const float4* xf = reinterpret_cast<const float4*>(x);
    float4 xa[2], xc[2];
    xa[0] = xf[(size_t)rA * 4];  xc[0] = xf[(size_t)rA * 4 + 1];
    xa[1] = xf[(size_t)rB * 4];  xc[1] = xf[(size_t)rB * 4 + 1];

    bool q0 = (vq == 0), qlt2 = (vq < 2);

    // ================= distributed weight-fragment prep =================
    // A[m][k]: m = lane&15, k = (lane>>4)*8 + j. Zero where k >= K_layer.
    if (wid == 0) {
        float4 w = reinterpret_cast<const float4*>(W1)[vn];   // W1 row vn, K=4
        u32 h0, l0, h1, l1; split2(w.x, w.y, h0, l0); split2(w.z, w.w, h1, l1);
        shfrag[0][lane] = make_uint4(q0 ? h0 : 0, q0 ? h1 : 0, 0, 0);
        shfrag[1][lane] = make_uint4(q0 ? l0 : 0, q0 ? l1 : 0, 0, 0);
    } else if (wid == 1) {
        // W2 tile a (rows 0..15; K=16, valid q<2; q>=2 reads aliased then zeroed)
        const float4* p0 = reinterpret_cast<const float4*>(W2 + vn * 16 + (vq & 1) * 8);
        float4 a0 = p0[0], a1 = p0[1];
        u32 h, l; uint4 H, L;
        split2(a0.x, a0.y, h, l); H.x = qlt2 ? h : 0; L.x = qlt2 ? l : 0;
        split2(a0.z, a0.w, h, l); H.y = qlt2 ? h : 0; L.y = qlt2 ? l : 0;
        split2(a1.x, a1.y, h, l); H.z = qlt2 ? h : 0; L.z = qlt2 ? l : 0;
        split2(a1.z, a1.w, h, l); H.w = qlt2 ? h : 0; L.w = qlt2 ? l : 0;
        shfrag[2][lane] = H; shfrag[3][lane] = L;
    } else if (wid == 2) {
        // W2 tile b (rows 16..31)
        const float4* p1 = reinterpret_cast<const float4*>(W2 + (16 + vn) * 16 + (vq & 1) * 8);
        float4 c0 = p1[0], c1v = p1[1];
        u32 h, l; uint4 H, L;
        split2(c0.x, c0.y, h, l); H.x = qlt2 ? h : 0; L.x = qlt2 ? l : 0;
        split2(c0.z, c0.w, h, l); H.y = qlt2 ? h : 0; L.y = qlt2 ? l : 0;
        split2(c1v.x, c1v.y, h, l); H.z = qlt2 ? h : 0; L.z = qlt2 ? l : 0;
        split2(c1v.z, c1v.w, h, l); H.w = qlt2 ? h : 0; L.w = qlt2 ? l : 0;
        shfrag[4][lane] = H; shfrag[5][lane] = L;
    } else {
        // W3 (K=32 exact, all lanes valid)
        const float4* p3 = reinterpret_cast<const float4*>(W3 + vn * 32 + vq * 8);
        float4 e0 = p3[0], e1 = p3[1];
        u32 h, l; uint4 H, L;
        split2(e0.x, e0.y, h, l); H.x = h; L.x = l;
        split2(e0.z, e0.w, h, l); H.y = h; L.y = l;
        split2(e1.x, e1.y, h, l); H.z = h; L.z = l;
        split2(e1.z, e1.w, h, l); H.w = h; L.w = l;
        shfrag[6][lane] = H; shfrag[7][lane] = L;
    }

    // ---- trainable-gate coefficients (uniform), hoisted out of row loop ----
    const float INV4PI = 0.07957747154594767f;
    v2f vcg[4], vsg[4];
    #pragma unroll
    for (int w = 0; w < 4; ++w) {
        float a = qw[2 * w];                 // uniform -> s_load
        vcg[w] = s2v(__builtin_amdgcn_cosf(a * INV4PI));
        vsg[w] = s2v(__builtin_amdgcn_sinf(a * INV4PI));
    }

    // ================= quantum circuit, 2 independent rows =================
    // Global-phase fold: u0 = (c, 0) REAL, u1 = s*(cos phi, sin phi).
    // v_sin/v_cos take revolutions: theta/2 = x*pi/2 -> x/4; phi = x'*pi -> x'/2.
    u32 zd0[2], zd1[2];
    #pragma unroll
    for (int rr = 0; rr < 2; ++rr) {
        float th[4]  = { xa[rr].x, xa[rr].y, xa[rr].z, xa[rr].w };
        float phv[4] = { xc[rr].x, xc[rr].y, xc[rr].z, xc[rr].w };
        float c4[4], u1r[4], u1i[4];
        #pragma unroll
        for (int i = 0; i < 4; ++i) {
            float c  = __builtin_amdgcn_cosf(th[i]  * 0.25f);
            float s  = __builtin_amdgcn_sinf(th[i]  * 0.25f);
            float cz = __builtin_amdgcn_cosf(phv[i] * 0.5f);
            float sz = __builtin_amdgcn_sinf(phv[i] * 0.5f);
            c4[i] = c; u1r[i] = s * cz; u1i[i] = s * sz;
        }
        // pair products; u0 real -> sparse (entry 0 purely real)
        float p01r[4], p01i[4], p23r[4], p23i[4];
        p01r[0] = c4[0] * c4[1];                          p01i[0] = 0.f;
        p01r[1] = c4[0] * u1r[1];                         p01i[1] = c4[0] * u1i[1];
        p01r[2] = u1r[0] * c4[1];                         p01i[2] = u1i[0] * c4[1];
        p01r[3] = u1r[0] * u1r[1] - u1i[0] * u1i[1];
        p01i[3] = u1r[0] * u1i[1] + u1i[0] * u1r[1];
        p23r[0] = c4[2] * c4[3];                          p23i[0] = 0.f;
        p23r[1] = c4[2] * u1r[3];                         p23i[1] = c4[2] * u1i[3];
        p23r[2] = u1r[2] * c4[3];                         p23i[2] = u1i[2] * c4[3];
        p23r[3] = u1r[2] * u1r[3] - u1i[2] * u1i[3];
        p23i[3] = u1r[2] * u1i[3] + u1i[2] * u1r[3];

        v2f amp[16];   // first CNOT chain folded: g(q)=(q0,q1^q0,q2^q1,q3^q2)
        #pragma unroll
        for (int i = 0; i < 16; ++i) {
            int q0i=(i>>3)&1, q1i=(i>>2)&1, q2i=(i>>1)&1, q3i=i&1;
            int g = (q0i<<3) | ((q1i^q0i)<<2) | ((q2i^q1i)<<1) | (q3i^q2i);
            int hi = g >> 2, lo = g & 3;
            float r, im;
            if (hi == 0) {
                if (lo == 0) { r = p01r[0] * p23r[0];  im = 0.f; }
                else         { r = p01r[0] * p23r[lo]; im = p01r[0] * p23i[lo]; }
            } else if (lo == 0) {
                r = p01r[hi] * p23r[0]; im = p01i[hi] * p23r[0];
            } else {
                r  = p01r[hi] * p23r[lo] - p01i[hi] * p23i[lo];
                im = p01r[hi] * p23i[lo] + p01i[hi] * p23r[lo];
            }
            amp[i] = (v2f){ r, im };
        }
        #pragma unroll
        for (int w = 0; w < 4; ++w) {           // trainable RY (RZ phase-invisible)
            v2f vc = vcg[w], vs = vsg[w];
            int stride = 1 << (3 - w);
            #pragma unroll
            for (int m = 0; m < 16; ++m) {
                if (m & stride) continue;
                int i0 = m, i1 = m | stride;
                v2f a0 = amp[i0], a1 = amp[i1];
                amp[i0] = pkfma(vc, a0, -(vs * a1));
                amp[i1] = pkfma(vc, a1,  (vs * a0));
            }
        }
        // second CNOT chain + |amp|^2, reductions kept packed
        v2f Pv[16];
        #pragma unroll
        for (int i = 0; i < 16; ++i) {
            int q0i=(i>>3)&1, q1i=(i>>2)&1, q2i=(i>>1)&1, q3i=i&1;
            int g = (q0i<<3) | ((q1i^q0i)<<2) | ((q2i^q1i)<<1) | (q3i^q2i);
            Pv[i] = amp[g] * amp[g];
        }
        v2f q2[8], q4[4];
        #pragma unroll
        for (int j = 0; j < 8; ++j) q2[j] = Pv[2*j] + Pv[2*j+1];
        #pragma unroll
        for (int j = 0; j < 4; ++j) q4[j] = q2[2*j] + q2[2*j+1];
        v2f z0v = (q4[0] + q4[1]) - (q4[2] + q4[3]);
        v2f z1v = (q4[0] - q4[1]) + (q4[2] - q4[3]);
        v2f z2v = (q2[0]-q2[1]) + (q2[2]-q2[3]) + (q2[4]-q2[5]) + (q2[6]-q2[7]);
        v2f z3v = (Pv[0]-Pv[1]) + (Pv[2]-Pv[3]) + (Pv[4]-Pv[5]) + (Pv[6]-Pv[7])
                + (Pv[8]-Pv[9]) + (Pv[10]-Pv[11]) + (Pv[12]-Pv[13]) + (Pv[14]-Pv[15]);
        float zv0 = z0v.x + z0v.y, zv1 = z1v.x + z1v.y;
        float zv2 = z2v.x + z2v.y, zv3 = z3v.x + z3v.y;

        // z packed bf16 pairs (k-order: low=even k)
        zd0[rr] = cvt_pk_bf16(zv0, zv1);
        zd1[rr] = cvt_pk_bf16(zv2, zv3);
    }

    // ---- pick up shared weight fragments ----
    __syncthreads();
    FragU A1h, A1l, A2ah, A2al, A2bh, A2bl, A3h, A3l;
    A1h.q  = shfrag[0][lane]; A1l.q  = shfrag[1][lane];
    A2ah.q = shfrag[2][lane]; A2al.q = shfrag[3][lane];
    A2bh.q = shfrag[4][lane]; A2bl.q = shfrag[5][lane];
    A3h.q  = shfrag[6][lane]; A3l.q  = shfrag[7][lane];

    // biases along C rows (features = quad*4+r)
    float4 c1b  = reinterpret_cast<const float4*>(b1)[vq];
    float4 c2b0 = reinterpret_cast<const float4*>(b2)[vq];
    float4 c2b1 = reinterpret_cast<const float4*>(b2)[4 + vq];
    float4 c3b  = reinterpret_cast<const float4*>(b3)[vq];

    // bpermute byte-indices for C->B transposes (mod-4 quad keeps idx in-wave)
    int i2a = ((((2 * vq)    ) & 3) * 16 + vn) * 4;
    int i2b = ((((2 * vq) + 1) & 3) * 16 + vn) * 4;

    // ================= MLP: 8 tiles of 16 rows per wave =================
    #pragma unroll
    for (int t = 0; t < 8; ++t) {
        u32 z0 = zd0[t >> 2], z1 = zd1[t >> 2];
        // L1: B = z^T gather (k<4 live; rest covered by A1 zeros)
        int viL = ((t & 3) * 16 + vn) * 4;
        FragU B1; B1.d[0] = bp(viL, z0); B1.d[1] = bp(viL, z1); B1.d[2] = 0; B1.d[3] = 0;
        f32x4 c1 = tov(c1b);
        c1 = MFMA16(A1l.s, B1.s, c1, 0, 0, 0);
        c1 = MFMA16(A1h.s, B1.s, c1, 0, 0, 0);
        u32 da0 = cvt_pk_bf16(fmaxf(c1[0], 0.f), fmaxf(c1[1], 0.f));   // features q*4+0,1
        u32 da1 = cvt_pk_bf16(fmaxf(c1[2], 0.f), fmaxf(c1[3], 0.f));   // features q*4+2,3

        // L2: B[k=h1 feature][n] via 4 bpermutes
        FragU B2;
        B2.d[0] = bp(i2a, da0); B2.d[1] = bp(i2a, da1);
        B2.d[2] = bp(i2b, da0); B2.d[3] = bp(i2b, da1);
        f32x4 ca = tov(c2b0), cb = tov(c2b1);
        ca = MFMA16(A2al.s, B2.s, ca, 0, 0, 0);
        ca = MFMA16(A2ah.s, B2.s, ca, 0, 0, 0);
        cb = MFMA16(A2bl.s, B2.s, cb, 0, 0, 0);
        cb = MFMA16(A2bh.s, B2.s, cb, 0, 0, 0);
        u32 ea0 = cvt_pk_bf16(fmaxf(ca[0],0.f), fmaxf(ca[1],0.f));   // features  q*4+0,1
        u32 ea1 = cvt_pk_bf16(fmaxf(ca[2],0.f), fmaxf(ca[3],0.f));
        u32 eb0 = cvt_pk_bf16(fmaxf(cb[0],0.f), fmaxf(cb[1],0.f));   // features 16+q*4+..
        u32 eb1 = cvt_pk_bf16(fmaxf(cb[2],0.f), fmaxf(cb[3],0.f));

        // L3: B over 32 features; tile-select (q<2 -> features<16) after
        // full-exec bpermutes (no divergent cross-lane ops)
        u32 s0a = bp(i2a, ea0), s0b = bp(i2a, eb0);
        u32 s1a = bp(i2a, ea1), s1b = bp(i2a, eb1);
        u32 s2_ = bp(i2b, ea0), s2b = bp(i2b, eb0);
        u32 s3a = bp(i2b, ea1), s3b = bp(i2b, eb1);
        FragU B3;
        B3.d[0] = qlt2 ? s0a : s0b;
        B3.d[1] = qlt2 ? s1a : s1b;
        B3.d[2] = qlt2 ? s2_ : s2b;
        B3.d[3] = qlt2 ? s3a : s3b;
        f32x4 c3 = tov(c3b);
        c3 = MFMA16(A3l.s, B3.s, c3, 0, 0, 0);
        c3 = MFMA16(A3h.s, B3.s, c3, 0, 0, 0);

        // store: row = batch (col n), features q*4..q*4+3 -> contiguous 16B
        int R = wavebase + t * 16 + vn;
        if (R < n)
            *reinterpret_cast<float4*>(out + (size_t)R * 16 + vq * 4) =
                make_float4(c3[0], c3[1], c3[2], c3[3]);
    }
}

extern "C" void kernel_launch(void* const* d_in, const int* in_sizes, int n_in,
                              void* d_out, int out_size, void* d_ws, size_t ws_size,
                              hipStream_t stream) {
    const float* x  = (const float*)d_in[0];
    const float* qw = (const float*)d_in[1];
    const float* W1 = (const float*)d_in[2];
    const float* b1 = (const float*)d_in[3];
    const float* W2 = (const float*)d_in[4];
    const float* b2 = (const float*)d_in[5];
    const float* W3 = (const float*)d_in[6];
    const float* b3 = (const float*)d_in[7];
    float* out = (float*)d_out;

    int n = in_sizes[0] / 16;             // B
    int blocks = (n + 511) / 512;
    qae_bperm<<<blocks, 256, 0, stream>>>(x, qw, W1, b1, W2, b2, W3, b3, out, n);
}

// Round 4
// 128.057 us; speedup vs baseline: 1.0063x; 1.0063x over previous
//
#include <hip/hip_runtime.h>

using u16 = unsigned short;
using u32 = unsigned int;
typedef float v2f   __attribute__((ext_vector_type(2)));
typedef float f32x4 __attribute__((ext_vector_type(4)));
typedef short s16x8 __attribute__((ext_vector_type(8)));

union FragU { u32 d[4]; s16x8 s; uint4 q; };

// Single-instruction RNE pack of two f32 -> packed bf16 {lo=a, hi=b}.
__device__ __forceinline__ u32 cvt_pk_bf16(float a, float b) {
    u32 r;
    asm("v_cvt_pk_bf16_f32 %0, %1, %2" : "=v"(r) : "v"(a), "v"(b));
    return r;
}
// weight split: hi = truncated bf16 pair, lo = RNE bf16 of exact residual
__device__ __forceinline__ void split2(float w0, float w1, u32& hi, u32& lo) {
    u32 u0 = __float_as_uint(w0), u1 = __float_as_uint(w1);
    hi = (u0 >> 16) | (u1 & 0xFFFF0000u);
    float r0 = w0 - __uint_as_float(u0 & 0xFFFF0000u);
    float r1 = w1 - __uint_as_float(u1 & 0xFFFF0000u);
    lo = cvt_pk_bf16(r0, r1);
}
__device__ __forceinline__ u32 bp(int ib, u32 v) {           // full-exec crossbar pull
    return (u32)__builtin_amdgcn_ds_bpermute(ib, (int)v);
}
__device__ __forceinline__ v2f pkfma(v2f a, v2f b, v2f c) { return __builtin_elementwise_fma(a, b, c); }
__device__ __forceinline__ v2f s2v(float x) { return (v2f){x, x}; }
__device__ __forceinline__ f32x4 tov(float4 v) { return (f32x4){v.x, v.y, v.z, v.w}; }
#define MFMA16 __builtin_amdgcn_mfma_f32_16x16x32_bf16

// Thread = 1 batch row (quantum part); wave = 64 rows = 4 MFMA tiles.
// hi/lo split-precision weights packed into UNUSED K-slots of each MFMA:
//   L1: Whi at k=0..3, Wlo at k=8..11 (B replicates z into every quad) -> 1 MFMA
//   L2: Whi at k=0..15, Wlo at k=16..31 (mod-4 bpermute already mirrors h1
//       into quads 2,3) -> 1 MFMA per 16-row output tile
//   L3: K=32 full -> genuine hi+lo pair (2 MFMAs)
__global__ void __launch_bounds__(256) qae_bperm(
    const float* __restrict__ x,  const float* __restrict__ qw,
    const float* __restrict__ W1, const float* __restrict__ b1,
    const float* __restrict__ W2, const float* __restrict__ b2,
    const float* __restrict__ W3, const float* __restrict__ b3,
    float* __restrict__ out, int n)
{
    int tid  = threadIdx.x;
    int b    = blockIdx.x * 256 + tid;
    int bc   = b < n ? b : n - 1;
    int lane = tid & 63;
    int wid  = tid >> 6;
    int vn   = lane & 15, vq = lane >> 4;
    int gbase = blockIdx.x * 256 + (tid - lane);     // wave's first global row

    __shared__ uint4 shfrag[5][64];      // 5 KB: A1, A2a, A2b, A3h, A3l

    // ---- x load first (HBM latency) ----
    const float4* xf = reinterpret_cast<const float4*>(x);
    float4 xa = xf[(size_t)bc * 4];
    float4 xc = xf[(size_t)bc * 4 + 1];

    bool q0 = (vq == 0), q1v = (vq == 1), qlt2 = (vq < 2);

    // ================= distributed weight-fragment prep =================
    // A[m][k]: m = lane&15, k = (lane>>4)*8 + j.
    if (wid == 0) {
        // A1: q=0 -> W1hi (k=0..3), q=1 -> W1lo (k=8..11), else 0
        float4 w = reinterpret_cast<const float4*>(W1)[vn];   // W1 row vn, K=4
        u32 h0, l0, h1, l1; split2(w.x, w.y, h0, l0); split2(w.z, w.w, h1, l1);
        u32 d0 = q0 ? h0 : (q1v ? l0 : 0);
        u32 d1 = q0 ? h1 : (q1v ? l1 : 0);
        shfrag[0][lane] = make_uint4(d0, d1, 0, 0);
    } else if (wid == 1) {
        // A2a (W2 rows 0..15): q<2 -> hi cols q*8.., q>=2 -> lo cols (q-2)*8..
        const float4* p0 = reinterpret_cast<const float4*>(W2 + vn * 16 + (vq & 1) * 8);
        float4 a0 = p0[0], a1 = p0[1];
        u32 h, l; uint4 H;
        split2(a0.x, a0.y, h, l); H.x = qlt2 ? h : l;
        split2(a0.z, a0.w, h, l); H.y = qlt2 ? h : l;
        split2(a1.x, a1.y, h, l); H.z = qlt2 ? h : l;
        split2(a1.z, a1.w, h, l); H.w = qlt2 ? h : l;
        shfrag[1][lane] = H;
    } else if (wid == 2) {
        // A2b (W2 rows 16..31): same packing
        const float4* p1 = reinterpret_cast<const float4*>(W2 + (16 + vn) * 16 + (vq & 1) * 8);
        float4 c0 = p1[0], c1v = p1[1];
        u32 h, l; uint4 H;
        split2(c0.x, c0.y, h, l);   H.x = qlt2 ? h : l;
        split2(c0.z, c0.w, h, l);   H.y = qlt2 ? h : l;
        split2(c1v.x, c1v.y, h, l); H.z = qlt2 ? h : l;
        split2(c1v.z, c1v.w, h, l); H.w = qlt2 ? h : l;
        shfrag[2][lane] = H;
    } else {
        // A3 (W3, K=32 exact): both hi and lo fragments
        const float4* p3 = reinterpret_cast<const float4*>(W3 + vn * 32 + vq * 8);
        float4 e0 = p3[0], e1 = p3[1];
        u32 h, l; uint4 H, L;
        split2(e0.x, e0.y, h, l); H.x = h; L.x = l;
        split2(e0.z, e0.w, h, l); H.y = h; L.y = l;
        split2(e1.x, e1.y, h, l); H.z = h; L.z = l;
        split2(e1.z, e1.w, h, l); H.w = h; L.w = l;
        shfrag[3][lane] = H; shfrag[4][lane] = L;
    }

    // ================= quantum circuit =================
    // Global-phase fold: u0 = (c, 0) REAL, u1 = s*(cos phi, sin phi).
    // v_sin/v_cos take revolutions: theta/2 = x*pi/2 -> x/4; phi = x'*pi -> x'/2.
    float th[4]  = { xa.x, xa.y, xa.z, xa.w };
    float phv[4] = { xc.x, xc.y, xc.z, xc.w };
    float c4[4], u1r[4], u1i[4];
    #pragma unroll
    for (int i = 0; i < 4; ++i) {
        float c  = __builtin_amdgcn_cosf(th[i]  * 0.25f);
        float s  = __builtin_amdgcn_sinf(th[i]  * 0.25f);
        float cz = __builtin_amdgcn_cosf(phv[i] * 0.5f);
        float sz = __builtin_amdgcn_sinf(phv[i] * 0.5f);
        c4[i] = c; u1r[i] = s * cz; u1i[i] = s * sz;
    }
    // pair products; u0 real -> sparse (entry 0 purely real)
    float p01r[4], p01i[4], p23r[4], p23i[4];
    p01r[0] = c4[0] * c4[1];                          p01i[0] = 0.f;
    p01r[1] = c4[0] * u1r[1];                         p01i[1] = c4[0] * u1i[1];
    p01r[2] = u1r[0] * c4[1];                         p01i[2] = u1i[0] * c4[1];
    p01r[3] = u1r[0] * u1r[1] - u1i[0] * u1i[1];
    p01i[3] = u1r[0] * u1i[1] + u1i[0] * u1r[1];
    p23r[0] = c4[2] * c4[3];                          p23i[0] = 0.f;
    p23r[1] = c4[2] * u1r[3];                         p23i[1] = c4[2] * u1i[3];
    p23r[2] = u1r[2] * c4[3];                         p23i[2] = u1i[2] * c4[3];
    p23r[3] = u1r[2] * u1r[3] - u1i[2] * u1i[3];
    p23i[3] = u1r[2] * u1i[3] + u1i[2] * u1r[3];

    v2f amp[16];   // first CNOT chain folded: g(q)=(q0,q1^q0,q2^q1,q3^q2)
    #pragma unroll
    for (int i = 0; i < 16; ++i) {
        int q0i=(i>>3)&1, q1i=(i>>2)&1, q2i=(i>>1)&1, q3i=i&1;
        int g = (q0i<<3) | ((q1i^q0i)<<2) | ((q2i^q1i)<<1) | (q3i^q2i);
        int hi = g >> 2, lo = g & 3;
        float r, im;
        if (hi == 0) {
            if (lo == 0) { r = p01r[0] * p23r[0];  im = 0.f; }
            else         { r = p01r[0] * p23r[lo]; im = p01r[0] * p23i[lo]; }
        } else if (lo == 0) {
            r = p01r[hi] * p23r[0]; im = p01i[hi] * p23r[0];
        } else {
            r  = p01r[hi] * p23r[lo] - p01i[hi] * p23i[lo];
            im = p01r[hi] * p23i[lo] + p01i[hi] * p23r[lo];
        }
        amp[i] = (v2f){ r, im };
    }
    const float INV4PI = 0.07957747154594767f;
    #pragma unroll
    for (int w = 0; w < 4; ++w) {           // trainable RY (RZ phase-invisible)
        float a = qw[2 * w];                 // uniform -> s_load
        v2f vc = s2v(__builtin_amdgcn_cosf(a * INV4PI));
        v2f vs = s2v(__builtin_amdgcn_sinf(a * INV4PI));
        int stride = 1 << (3 - w);
        #pragma unroll
        for (int m = 0; m < 16; ++m) {
            if (m & stride) continue;
            int i0 = m, i1 = m | stride;
            v2f a0 = amp[i0], a1 = amp[i1];
            amp[i0] = pkfma(vc, a0, -(vs * a1));
            amp[i1] = pkfma(vc, a1,  (vs * a0));
        }
    }
    // second CNOT chain + |amp|^2, reductions kept packed (r,i summed at end)
    v2f Pv[16];
    #pragma unroll
    for (int i = 0; i < 16; ++i) {
        int q0i=(i>>3)&1, q1i=(i>>2)&1, q2i=(i>>1)&1, q3i=i&1;
        int g = (q0i<<3) | ((q1i^q0i)<<2) | ((q2i^q1i)<<1) | (q3i^q2i);
        Pv[i] = amp[g] * amp[g];
    }
    v2f q2[8], q4[4];
    #pragma unroll
    for (int j = 0; j < 8; ++j) q2[j] = Pv[2*j] + Pv[2*j+1];
    #pragma unroll
    for (int j = 0; j < 4; ++j) q4[j] = q2[2*j] + q2[2*j+1];
    v2f z0v = (q4[0] + q4[1]) - (q4[2] + q4[3]);
    v2f z1v = (q4[0] - q4[1]) + (q4[2] - q4[3]);
    v2f z2v = (q2[0]-q2[1]) + (q2[2]-q2[3]) + (q2[4]-q2[5]) + (q2[6]-q2[7]);
    v2f z3v = (Pv[0]-Pv[1]) + (Pv[2]-Pv[3]) + (Pv[4]-Pv[5]) + (Pv[6]-Pv[7])
            + (Pv[8]-Pv[9]) + (Pv[10]-Pv[11]) + (Pv[12]-Pv[13]) + (Pv[14]-Pv[15]);
    float zv0 = z0v.x + z0v.y, zv1 = z1v.x + z1v.y;
    float zv2 = z2v.x + z2v.y, zv3 = z3v.x + z3v.y;

    // z packed bf16 pairs (k-order: low=even k)
    u32 zd0 = cvt_pk_bf16(zv0, zv1);
    u32 zd1 = cvt_pk_bf16(zv2, zv3);

    // ---- pick up shared weight fragments ----
    __syncthreads();
    FragU A1, A2a, A2b, A3h, A3l;
    A1.q  = shfrag[0][lane];
    A2a.q = shfrag[1][lane];
    A2b.q = shfrag[2][lane];
    A3h.q = shfrag[3][lane];
    A3l.q = shfrag[4][lane];

    // biases along C rows (features = quad*4+r)
    float4 c1b  = reinterpret_cast<const float4*>(b1)[vq];
    float4 c2b0 = reinterpret_cast<const float4*>(b2)[vq];
    float4 c2b1 = reinterpret_cast<const float4*>(b2)[4 + vq];
    float4 c3b  = reinterpret_cast<const float4*>(b3)[vq];

    // bpermute byte-indices for C->B transposes (mod-4 quad keeps idx in-wave;
    // quads 2,3 mirror 0,1 -> h1 lands at k=16..31 where W2lo sits)
    int i2a = ((((2 * vq)    ) & 3) * 16 + vn) * 4;
    int i2b = ((((2 * vq) + 1) & 3) * 16 + vn) * 4;

    // ================= MLP: 4 tiles of 16 rows per wave =================
    #pragma unroll
    for (int t = 0; t < 4; ++t) {
        // L1: B = z^T gather; every quad's k-slice holds z -> hi(k0..3)+lo(k8..11)
        int viL = (t * 16 + vn) * 4;
        FragU B1; B1.d[0] = bp(viL, zd0); B1.d[1] = bp(viL, zd1); B1.d[2] = 0; B1.d[3] = 0;
        f32x4 c1 = tov(c1b);
        c1 = MFMA16(A1.s, B1.s, c1, 0, 0, 0);
        u32 da0 = cvt_pk_bf16(fmaxf(c1[0], 0.f), fmaxf(c1[1], 0.f));   // features q*4+0,1
        u32 da1 = cvt_pk_bf16(fmaxf(c1[2], 0.f), fmaxf(c1[3], 0.f));   // features q*4+2,3

        // L2: B[k][n] via 4 bpermutes; k=0..15 = h1 (hi), k=16..31 = h1 again (lo)
        FragU B2;
        B2.d[0] = bp(i2a, da0); B2.d[1] = bp(i2a, da1);
        B2.d[2] = bp(i2b, da0); B2.d[3] = bp(i2b, da1);
        f32x4 ca = tov(c2b0), cb = tov(c2b1);
        ca = MFMA16(A2a.s, B2.s, ca, 0, 0, 0);
        cb = MFMA16(A2b.s, B2.s, cb, 0, 0, 0);
        u32 ea0 = cvt_pk_bf16(fmaxf(ca[0],0.f), fmaxf(ca[1],0.f));   // features  q*4+0,1
        u32 ea1 = cvt_pk_bf16(fmaxf(ca[2],0.f), fmaxf(ca[3],0.f));
        u32 eb0 = cvt_pk_bf16(fmaxf(cb[0],0.f), fmaxf(cb[1],0.f));   // features 16+q*4+..
        u32 eb1 = cvt_pk_bf16(fmaxf(cb[2],0.f), fmaxf(cb[3],0.f));

        // L3: B over 32 features; tile-select (q<2 -> features<16) after
        // full-exec bpermutes (no divergent cross-lane ops)
        u32 s0a = bp(i2a, ea0), s0b = bp(i2a, eb0);
        u32 s1a = bp(i2a, ea1), s1b = bp(i2a, eb1);
        u32 s2_ = bp(i2b, ea0), s2b = bp(i2b, eb0);
        u32 s3a = bp(i2b, ea1), s3b = bp(i2b, eb1);
        FragU B3;
        B3.d[0] = qlt2 ? s0a : s0b;
        B3.d[1] = qlt2 ? s1a : s1b;
        B3.d[2] = qlt2 ? s2_ : s2b;
        B3.d[3] = qlt2 ? s3a : s3b;
        f32x4 c3 = tov(c3b);
        c3 = MFMA16(A3l.s, B3.s, c3, 0, 0, 0);
        c3 = MFMA16(A3h.s, B3.s, c3, 0, 0, 0);

        // store: row = batch (col n), features q*4..q*4+3 -> contiguous 16B
        int R = gbase + t * 16 + vn;
        if (R < n)
            *reinterpret_cast<float4*>(out + (size_t)R * 16 + vq * 4) =
                make_float4(c3[0], c3[1], c3[2], c3[3]);
    }
}

extern "C" void kernel_launch(void* const* d_in, const int* in_sizes, int n_in,
                              void* d_out, int out_size, void* d_ws, size_t ws_size,
                              hipStream_t stream) {
    const float* x  = (const float*)d_in[0];
    const float* qw = (const float*)d_in[1];
    const float* W1 = (const float*)d_in[2];
    const float* b1 = (const float*)d_in[3];
    const float* W2 = (const float*)d_in[4];
    const float* b2 = (const float*)d_in[5];
    const float* W3 = (const float*)d_in[6];
    const float* b3 = (const float*)d_in[7];
    float* out = (float*)d_out;

    int n = in_sizes[0] / 16;             // B
    int blocks = (n + 255) / 256;
    qae_bperm<<<blocks, 256, 0, stream>>>(x, qw, W1, b1, W2, b2, W3, b3, out, n);
}

// Round 5
// 125.427 us; speedup vs baseline: 1.0274x; 1.0210x over previous
//
#include <hip/hip_runtime.h>

using u16 = unsigned short;
using u32 = unsigned int;
typedef float f32x4 __attribute__((ext_vector_type(4)));
typedef short s16x8 __attribute__((ext_vector_type(8)));

union FragU { u32 d[4]; s16x8 s; uint4 q; };

// Single-instruction RNE pack of two f32 -> packed bf16 {lo=a, hi=b}.
__device__ __forceinline__ u32 cvt_pk_bf16(float a, float b) {
    u32 r;
    asm("v_cvt_pk_bf16_f32 %0, %1, %2" : "=v"(r) : "v"(a), "v"(b));
    return r;
}
// weight split: hi = truncated bf16 pair, lo = RNE bf16 of exact residual
__device__ __forceinline__ void split2(float w0, float w1, u32& hi, u32& lo) {
    u32 u0 = __float_as_uint(w0), u1 = __float_as_uint(w1);
    hi = (u0 >> 16) | (u1 & 0xFFFF0000u);
    float r0 = w0 - __uint_as_float(u0 & 0xFFFF0000u);
    float r1 = w1 - __uint_as_float(u1 & 0xFFFF0000u);
    lo = cvt_pk_bf16(r0, r1);
}
__device__ __forceinline__ u32 bp(int ib, u32 v) {           // full-exec crossbar pull
    return (u32)__builtin_amdgcn_ds_bpermute(ib, (int)v);
}
__device__ __forceinline__ f32x4 tov(float4 v) { return (f32x4){v.x, v.y, v.z, v.w}; }
#define MFMA16 __builtin_amdgcn_mfma_f32_16x16x32_bf16

// Thread = 1 batch row; wave = 64 rows = 4 MFMA tiles.
// Quantum encoder evaluated in CLOSED FORM (no state-vector simulation):
//   Conjugate Z_w through the 2nd CNOT chain: O_w = Z0..Zw. Trainable RZs are
//   diagonal -> drop. Trainable RYs: Z_v -> cos(a_v) Z_v - sin(a_v) X_v.
//   Expectation in psi1 = C1 |product> factorizes per qubit into
//   Zb=cos(th), Xb=sin(th)cos(ph), Yb=sin(th)sin(ph)  (th=pi*x_i, ph=pi*x_{i+4}).
//   Derivation hand-verified against direct simulation on 5 entangling cases.
__global__ void __launch_bounds__(256) qae_bperm(
    const float* __restrict__ x,  const float* __restrict__ qw,
    const float* __restrict__ W1, const float* __restrict__ b1,
    const float* __restrict__ W2, const float* __restrict__ b2,
    const float* __restrict__ W3, const float* __restrict__ b3,
    float* __restrict__ out, int n)
{
    int tid  = threadIdx.x;
    int b    = blockIdx.x * 256 + tid;
    int bc   = b < n ? b : n - 1;
    int lane = tid & 63;
    int wid  = tid >> 6;
    int vn   = lane & 15, vq = lane >> 4;
    int gbase = blockIdx.x * 256 + (tid - lane);     // wave's first global row

    __shared__ uint4 shfrag[5][64];      // 5 KB: A1, A2a, A2b, A3h, A3l

    // ---- x load first (HBM latency) ----
    const float4* xf = reinterpret_cast<const float4*>(x);
    float4 xa = xf[(size_t)bc * 4];
    float4 xc = xf[(size_t)bc * 4 + 1];

    bool q0 = (vq == 0), q1v = (vq == 1), qlt2 = (vq < 2);

    // ================= distributed weight-fragment prep =================
    // A[m][k]: m = lane&15, k = (lane>>4)*8 + j.  hi/lo packed into K-slots:
    //   L1: Whi k=0..3, Wlo k=8..11; L2: Whi k=0..15, Wlo k=16..31; L3: true pair.
    if (wid == 0) {
        float4 w = reinterpret_cast<const float4*>(W1)[vn];   // W1 row vn, K=4
        u32 h0, l0, h1, l1; split2(w.x, w.y, h0, l0); split2(w.z, w.w, h1, l1);
        u32 d0 = q0 ? h0 : (q1v ? l0 : 0);
        u32 d1 = q0 ? h1 : (q1v ? l1 : 0);
        shfrag[0][lane] = make_uint4(d0, d1, 0, 0);
    } else if (wid == 1) {
        const float4* p0 = reinterpret_cast<const float4*>(W2 + vn * 16 + (vq & 1) * 8);
        float4 a0 = p0[0], a1 = p0[1];
        u32 h, l; uint4 H;
        split2(a0.x, a0.y, h, l); H.x = qlt2 ? h : l;
        split2(a0.z, a0.w, h, l); H.y = qlt2 ? h : l;
        split2(a1.x, a1.y, h, l); H.z = qlt2 ? h : l;
        split2(a1.z, a1.w, h, l); H.w = qlt2 ? h : l;
        shfrag[1][lane] = H;
    } else if (wid == 2) {
        const float4* p1 = reinterpret_cast<const float4*>(W2 + (16 + vn) * 16 + (vq & 1) * 8);
        float4 c0 = p1[0], c1v = p1[1];
        u32 h, l; uint4 H;
        split2(c0.x, c0.y, h, l);   H.x = qlt2 ? h : l;
        split2(c0.z, c0.w, h, l);   H.y = qlt2 ? h : l;
        split2(c1v.x, c1v.y, h, l); H.z = qlt2 ? h : l;
        split2(c1v.z, c1v.w, h, l); H.w = qlt2 ? h : l;
        shfrag[2][lane] = H;
    } else {
        const float4* p3 = reinterpret_cast<const float4*>(W3 + vn * 32 + vq * 8);
        float4 e0 = p3[0], e1 = p3[1];
        u32 h, l; uint4 H, L;
        split2(e0.x, e0.y, h, l); H.x = h; L.x = l;
        split2(e0.z, e0.w, h, l); H.y = h; L.y = l;
        split2(e1.x, e1.y, h, l); H.z = h; L.z = l;
        split2(e1.z, e1.w, h, l); H.w = h; L.w = l;
        shfrag[3][lane] = H; shfrag[4][lane] = L;
    }

    // ================= closed-form quantum observables =================
    // v_sin/v_cos take revolutions: full angle pi*x -> x/2 rev.
    float th[4]  = { xa.x, xa.y, xa.z, xa.w };
    float phv[4] = { xc.x, xc.y, xc.z, xc.w };
    float Zb[4], Xb[4], Yb[4];
    #pragma unroll
    for (int i = 0; i < 4; ++i) {
        float ct = __builtin_amdgcn_cosf(th[i]  * 0.5f);
        float st = __builtin_amdgcn_sinf(th[i]  * 0.5f);
        float cp = __builtin_amdgcn_cosf(phv[i] * 0.5f);
        float sp = __builtin_amdgcn_sinf(phv[i] * 0.5f);
        Zb[i] = ct; Xb[i] = st * cp; Yb[i] = st * sp;
    }
    // trainable RY full angles (uniform across lanes)
    const float INV2PI = 0.15915494309189535f;
    float CA[4], SA[4];
    #pragma unroll
    for (int v = 0; v < 4; ++v) {
        float a = qw[2 * v] * INV2PI;
        CA[v] = __builtin_amdgcn_cosf(a);
        SA[v] = __builtin_amdgcn_sinf(a);
    }
    float K00 = CA[0]*CA[1], K10 = SA[0]*CA[1], K01 = CA[0]*SA[1], K11 = SA[0]*SA[1];
    float L00 = CA[2]*CA[3], L10 = SA[2]*CA[3], L01 = CA[2]*SA[3], L11 = SA[2]*SA[3];
    // shared monomials
    float X01 = Xb[0]*Xb[1], Y01 = Yb[0]*Yb[1];
    float X23 = Xb[2]*Xb[3], Y23 = Yb[2]*Yb[3];

    // z0 = <Z0'>
    float zv0 = CA[0]*Zb[0] - SA[0]*X01;
    // z1 = <Z0'Z1'>
    float zv1 = K00*Zb[1] - K01*(Zb[0]*Xb[1]*Xb[2]) + K10*Y01 + K11*(Xb[0]*Xb[2]);
    // z2 = <Z0'Z1'Z2'>
    float t2a =  CA[2]*(Zb[0]*Zb[2])        - SA[2]*(Zb[1]*X23);
    float t2b = -CA[2]*(X01*Zb[2])          - SA[2]*(Y01*X23);
    float t2c =  CA[2]*(Yb[1]*Yb[2])        + SA[2]*(Zb[0]*Xb[1]*Xb[3]);
    float t2d = -CA[2]*(Yb[0]*Zb[1]*Yb[2])  - SA[2]*(Xb[0]*Xb[3]);
    float zv2 = K00*t2a + K10*t2b + K01*t2c + K11*t2d;
    // z3 = <Z0'Z1'Z2'Z3'>
    float t3a =  L00*(Zb[1]*Zb[3])              + L10*(Zb[0]*Y23)
               - L01*(Zb[0]*Zb[2]*Xb[3])        + L11*(Zb[1]*Xb[2]);
    float t3b =  L00*(Y01*Zb[3])                - L10*(X01*Y23)
               + L01*(X01*Zb[2]*Xb[3])          + L11*(Y01*Xb[2]);
    float t3c = -L00*(Zb[0]*Xb[1]*Xb[2]*Zb[3])  - L10*(Yb[1]*Zb[2]*Yb[3])
               - L01*(Yb[1]*Yb[2]*Xb[3])        - L11*(Zb[0]*Xb[1]);
    float t3d =  L00*(Xb[0]*Xb[2]*Zb[3])        + L10*(Yb[0]*Zb[1]*Zb[2]*Yb[3])
               + L01*(Yb[0]*Zb[1]*Yb[2]*Xb[3])  + L11*Xb[0];
    float zv3 = K00*t3a + K10*t3b + K01*t3c + K11*t3d;

    // z packed bf16 pairs (k-order: low=even k)
    u32 zd0 = cvt_pk_bf16(zv0, zv1);
    u32 zd1 = cvt_pk_bf16(zv2, zv3);

    // ---- pick up shared weight fragments ----
    __syncthreads();
    FragU A1, A2a, A2b, A3h, A3l;
    A1.q  = shfrag[0][lane];
    A2a.q = shfrag[1][lane];
    A2b.q = shfrag[2][lane];
    A3h.q = shfrag[3][lane];
    A3l.q = shfrag[4][lane];

    // biases along C rows (features = quad*4+r)
    float4 c1b  = reinterpret_cast<const float4*>(b1)[vq];
    float4 c2b0 = reinterpret_cast<const float4*>(b2)[vq];
    float4 c2b1 = reinterpret_cast<const float4*>(b2)[4 + vq];
    float4 c3b  = reinterpret_cast<const float4*>(b3)[vq];

    // bpermute byte-indices for C->B transposes (mod-4 quad keeps idx in-wave;
    // quads 2,3 mirror 0,1 -> h1 lands at k=16..31 where W2lo sits)
    int i2a = ((((2 * vq)    ) & 3) * 16 + vn) * 4;
    int i2b = ((((2 * vq) + 1) & 3) * 16 + vn) * 4;

    // ================= MLP: 4 tiles of 16 rows per wave =================
    #pragma unroll
    for (int t = 0; t < 4; ++t) {
        // L1: B = z^T gather; every quad's k-slice holds z -> hi(k0..3)+lo(k8..11)
        int viL = (t * 16 + vn) * 4;
        FragU B1; B1.d[0] = bp(viL, zd0); B1.d[1] = bp(viL, zd1); B1.d[2] = 0; B1.d[3] = 0;
        f32x4 c1 = tov(c1b);
        c1 = MFMA16(A1.s, B1.s, c1, 0, 0, 0);
        u32 da0 = cvt_pk_bf16(fmaxf(c1[0], 0.f), fmaxf(c1[1], 0.f));   // features q*4+0,1
        u32 da1 = cvt_pk_bf16(fmaxf(c1[2], 0.f), fmaxf(c1[3], 0.f));   // features q*4+2,3

        // L2: B[k][n] via 4 bpermutes; k=0..15 = h1 (hi), k=16..31 = h1 again (lo)
        FragU B2;
        B2.d[0] = bp(i2a, da0); B2.d[1] = bp(i2a, da1);
        B2.d[2] = bp(i2b, da0); B2.d[3] = bp(i2b, da1);
        f32x4 ca = tov(c2b0), cb = tov(c2b1);
        ca = MFMA16(A2a.s, B2.s, ca, 0, 0, 0);
        cb = MFMA16(A2b.s, B2.s, cb, 0, 0, 0);
        u32 ea0 = cvt_pk_bf16(fmaxf(ca[0],0.f), fmaxf(ca[1],0.f));   // features  q*4+0,1
        u32 ea1 = cvt_pk_bf16(fmaxf(ca[2],0.f), fmaxf(ca[3],0.f));
        u32 eb0 = cvt_pk_bf16(fmaxf(cb[0],0.f), fmaxf(cb[1],0.f));   // features 16+q*4+..
        u32 eb1 = cvt_pk_bf16(fmaxf(cb[2],0.f), fmaxf(cb[3],0.f));

        // L3: B over 32 features; tile-select (q<2 -> features<16) after
        // full-exec bpermutes (no divergent cross-lane ops)
        u32 s0a = bp(i2a, ea0), s0b = bp(i2a, eb0);
        u32 s1a = bp(i2a, ea1), s1b = bp(i2a, eb1);
        u32 s2_ = bp(i2b, ea0), s2b = bp(i2b, eb0);
        u32 s3a = bp(i2b, ea1), s3b = bp(i2b, eb1);
        FragU B3;
        B3.d[0] = qlt2 ? s0a : s0b;
        B3.d[1] = qlt2 ? s1a : s1b;
        B3.d[2] = qlt2 ? s2_ : s2b;
        B3.d[3] = qlt2 ? s3a : s3b;
        f32x4 c3 = tov(c3b);
        c3 = MFMA16(A3l.s, B3.s, c3, 0, 0, 0);
        c3 = MFMA16(A3h.s, B3.s, c3, 0, 0, 0);

        // store: row = batch (col n), features q*4..q*4+3 -> contiguous 16B
        int R = gbase + t * 16 + vn;
        if (R < n)
            *reinterpret_cast<float4*>(out + (size_t)R * 16 + vq * 4) =
                make_float4(c3[0], c3[1], c3[2], c3[3]);
    }
}

extern "C" void kernel_launch(void* const* d_in, const int* in_sizes, int n_in,
                              void* d_out, int out_size, void* d_ws, size_t ws_size,
                              hipStream_t stream) {
    const float* x  = (const float*)d_in[0];
    const float* qw = (const float*)d_in[1];
    const float* W1 = (const float*)d_in[2];
    const float* b1 = (const float*)d_in[3];
    const float* W2 = (const float*)d_in[4];
    const float* b2 = (const float*)d_in[5];
    const float* W3 = (const float*)d_in[6];
    const float* b3 = (const float*)d_in[7];
    float* out = (float*)d_out;

    int n = in_sizes[0] / 16;             // B
    int blocks = (n + 255) / 256;
    qae_bperm<<<blocks, 256, 0, stream>>>(x, qw, W1, b1, W2, b2, W3, b3, out, n);
}

// Round 6
// 125.011 us; speedup vs baseline: 1.0309x; 1.0033x over previous
//
#include <hip/hip_runtime.h>

using u16 = unsigned short;
using u32 = unsigned int;
typedef float f32x4 __attribute__((ext_vector_type(4)));
typedef short s16x8 __attribute__((ext_vector_type(8)));

union FragU { u32 d[4]; s16x8 s; uint4 q; };

// Single-instruction RNE pack of two f32 -> packed bf16 {lo=a, hi=b}.
__device__ __forceinline__ u32 cvt_pk_bf16(float a, float b) {
    u32 r;
    asm("v_cvt_pk_bf16_f32 %0, %1, %2" : "=v"(r) : "v"(a), "v"(b));
    return r;
}
// weight split: hi = truncated bf16 pair, lo = RNE bf16 of exact residual
__device__ __forceinline__ void split2(float w0, float w1, u32& hi, u32& lo) {
    u32 u0 = __float_as_uint(w0), u1 = __float_as_uint(w1);
    hi = (u0 >> 16) | (u1 & 0xFFFF0000u);
    float r0 = w0 - __uint_as_float(u0 & 0xFFFF0000u);
    float r1 = w1 - __uint_as_float(u1 & 0xFFFF0000u);
    lo = cvt_pk_bf16(r0, r1);
}
__device__ __forceinline__ u32 bp(int ib, u32 v) {           // full-exec crossbar pull
    return (u32)__builtin_amdgcn_ds_bpermute(ib, (int)v);
}
__device__ __forceinline__ f32x4 tov(float4 v) { return (f32x4){v.x, v.y, v.z, v.w}; }
#define MFMA16 __builtin_amdgcn_mfma_f32_16x16x32_bf16

// Thread = 1 batch row; wave = 64 rows = 4 MFMA tiles.
// FULLY DECOUPLED WAVES: no LDS, no __syncthreads. Each wave builds its own
// K-packed weight fragments (cheap now: ~140 VALU, loads hit L1/L2 since all
// waves read identical addresses).
// Quantum encoder in CLOSED FORM (see r5): O_w = Z0..Zw conjugated through the
// CNOT chain; RZs diagonal -> drop; RYs rotate Z_v -> cos a_v Z_v - sin a_v X_v;
// product-state expectations factorize: Zb=cos th, Xb=sin th cos ph, Yb=sin th sin ph.
// hi/lo split-precision weights packed into unused K-slots:
//   L1: Whi k=0..3, Wlo k=8..11 (B replicates z into every quad)   -> 1 MFMA
//   L2: Whi k=0..15, Wlo k=16..31 (bpermute mirrors h1 to quads 2,3)-> 1 MFMA/tile-half
//   L3: K=32 full -> genuine hi+lo pair (2 MFMAs)
__global__ void __launch_bounds__(256) qae_bperm(
    const float* __restrict__ x,  const float* __restrict__ qw,
    const float* __restrict__ W1, const float* __restrict__ b1,
    const float* __restrict__ W2, const float* __restrict__ b2,
    const float* __restrict__ W3, const float* __restrict__ b3,
    float* __restrict__ out, int n)
{
    int tid  = threadIdx.x;
    int b    = blockIdx.x * 256 + tid;
    int bc   = b < n ? b : n - 1;
    int lane = tid & 63;
    int vn   = lane & 15, vq = lane >> 4;
    int gbase = blockIdx.x * 256 + (tid - lane);     // wave's first global row

    // ---- all global loads issued first (hide L2/HBM latency) ----
    const float4* xf = reinterpret_cast<const float4*>(x);
    float4 xa = xf[(size_t)bc * 4];
    float4 xc = xf[(size_t)bc * 4 + 1];

    float4 w1r = reinterpret_cast<const float4*>(W1)[vn];                    // W1 row vn, K=4
    const float4* p0 = reinterpret_cast<const float4*>(W2 + vn * 16 + (vq & 1) * 8);
    float4 a0 = p0[0], a1 = p0[1];                                           // W2 rows 0..15
    const float4* p1 = reinterpret_cast<const float4*>(W2 + (16 + vn) * 16 + (vq & 1) * 8);
    float4 c0 = p1[0], c1v = p1[1];                                          // W2 rows 16..31
    const float4* p3 = reinterpret_cast<const float4*>(W3 + vn * 32 + vq * 8);
    float4 e0 = p3[0], e1 = p3[1];                                           // W3, K=32

    float4 c1b  = reinterpret_cast<const float4*>(b1)[vq];
    float4 c2b0 = reinterpret_cast<const float4*>(b2)[vq];
    float4 c2b1 = reinterpret_cast<const float4*>(b2)[4 + vq];
    float4 c3b  = reinterpret_cast<const float4*>(b3)[vq];

    bool q0 = (vq == 0), q1v = (vq == 1), qlt2 = (vq < 2);

    // ================= per-wave weight-fragment prep (K-packed) =================
    // A[m][k]: m = lane&15, k = (lane>>4)*8 + j.
    FragU A1, A2a, A2b, A3h, A3l;
    {
        u32 h0, l0, h1, l1; split2(w1r.x, w1r.y, h0, l0); split2(w1r.z, w1r.w, h1, l1);
        A1.d[0] = q0 ? h0 : (q1v ? l0 : 0);
        A1.d[1] = q0 ? h1 : (q1v ? l1 : 0);
        A1.d[2] = 0; A1.d[3] = 0;
        u32 h, l;
        split2(a0.x, a0.y, h, l);   A2a.d[0] = qlt2 ? h : l;
        split2(a0.z, a0.w, h, l);   A2a.d[1] = qlt2 ? h : l;
        split2(a1.x, a1.y, h, l);   A2a.d[2] = qlt2 ? h : l;
        split2(a1.z, a1.w, h, l);   A2a.d[3] = qlt2 ? h : l;
        split2(c0.x, c0.y, h, l);   A2b.d[0] = qlt2 ? h : l;
        split2(c0.z, c0.w, h, l);   A2b.d[1] = qlt2 ? h : l;
        split2(c1v.x, c1v.y, h, l); A2b.d[2] = qlt2 ? h : l;
        split2(c1v.z, c1v.w, h, l); A2b.d[3] = qlt2 ? h : l;
        split2(e0.x, e0.y, h, l);   A3h.d[0] = h; A3l.d[0] = l;
        split2(e0.z, e0.w, h, l);   A3h.d[1] = h; A3l.d[1] = l;
        split2(e1.x, e1.y, h, l);   A3h.d[2] = h; A3l.d[2] = l;
        split2(e1.z, e1.w, h, l);   A3h.d[3] = h; A3l.d[3] = l;
    }

    // ================= closed-form quantum observables =================
    // v_sin/v_cos take revolutions: full angle pi*x -> x/2 rev.
    float th[4]  = { xa.x, xa.y, xa.z, xa.w };
    float phv[4] = { xc.x, xc.y, xc.z, xc.w };
    float Zb[4], Xb[4], Yb[4];
    #pragma unroll
    for (int i = 0; i < 4; ++i) {
        float ct = __builtin_amdgcn_cosf(th[i]  * 0.5f);
        float st = __builtin_amdgcn_sinf(th[i]  * 0.5f);
        float cp = __builtin_amdgcn_cosf(phv[i] * 0.5f);
        float sp = __builtin_amdgcn_sinf(phv[i] * 0.5f);
        Zb[i] = ct; Xb[i] = st * cp; Yb[i] = st * sp;
    }
    // trainable RY full angles (uniform across lanes)
    const float INV2PI = 0.15915494309189535f;
    float CA[4], SA[4];
    #pragma unroll
    for (int v = 0; v < 4; ++v) {
        float a = qw[2 * v] * INV2PI;
        CA[v] = __builtin_amdgcn_cosf(a);
        SA[v] = __builtin_amdgcn_sinf(a);
    }
    float K00 = CA[0]*CA[1], K10 = SA[0]*CA[1], K01 = CA[0]*SA[1], K11 = SA[0]*SA[1];
    float L00 = CA[2]*CA[3], L10 = SA[2]*CA[3], L01 = CA[2]*SA[3], L11 = SA[2]*SA[3];
    // shared monomials
    float X01 = Xb[0]*Xb[1], Y01 = Yb[0]*Yb[1];
    float X23 = Xb[2]*Xb[3], Y23 = Yb[2]*Yb[3];

    // z0 = <Z0'>
    float zv0 = CA[0]*Zb[0] - SA[0]*X01;
    // z1 = <Z0'Z1'>
    float zv1 = K00*Zb[1] - K01*(Zb[0]*Xb[1]*Xb[2]) + K10*Y01 + K11*(Xb[0]*Xb[2]);
    // z2 = <Z0'Z1'Z2'>
    float t2a =  CA[2]*(Zb[0]*Zb[2])        - SA[2]*(Zb[1]*X23);
    float t2b = -CA[2]*(X01*Zb[2])          - SA[2]*(Y01*X23);
    float t2c =  CA[2]*(Yb[1]*Yb[2])        + SA[2]*(Zb[0]*Xb[1]*Xb[3]);
    float t2d = -CA[2]*(Yb[0]*Zb[1]*Yb[2])  - SA[2]*(Xb[0]*Xb[3]);
    float zv2 = K00*t2a + K10*t2b + K01*t2c + K11*t2d;
    // z3 = <Z0'Z1'Z2'Z3'>
    float t3a =  L00*(Zb[1]*Zb[3])              + L10*(Zb[0]*Y23)
               - L01*(Zb[0]*Zb[2]*Xb[3])        + L11*(Zb[1]*Xb[2]);
    float t3b =  L00*(Y01*Zb[3])                - L10*(X01*Y23)
               + L01*(X01*Zb[2]*Xb[3])          + L11*(Y01*Xb[2]);
    float t3c = -L00*(Zb[0]*Xb[1]*Xb[2]*Zb[3])  - L10*(Yb[1]*Zb[2]*Yb[3])
               - L01*(Yb[1]*Yb[2]*Xb[3])        - L11*(Zb[0]*Xb[1]);
    float t3d =  L00*(Xb[0]*Xb[2]*Zb[3])        + L10*(Yb[0]*Zb[1]*Zb[2]*Yb[3])
               + L01*(Yb[0]*Zb[1]*Yb[2]*Xb[3])  + L11*Xb[0];
    float zv3 = K00*t3a + K10*t3b + K01*t3c + K11*t3d;

    // z packed bf16 pairs (k-order: low=even k)
    u32 zd0 = cvt_pk_bf16(zv0, zv1);
    u32 zd1 = cvt_pk_bf16(zv2, zv3);

    // bpermute byte-indices for C->B transposes (mod-4 quad keeps idx in-wave;
    // quads 2,3 mirror 0,1 -> h1 lands at k=16..31 where W2lo sits)
    int i2a = ((((2 * vq)    ) & 3) * 16 + vn) * 4;
    int i2b = ((((2 * vq) + 1) & 3) * 16 + vn) * 4;

    // ================= MLP: 4 tiles of 16 rows per wave =================
    #pragma unroll
    for (int t = 0; t < 4; ++t) {
        // L1: B = z^T gather; every quad's k-slice holds z -> hi(k0..3)+lo(k8..11)
        int viL = (t * 16 + vn) * 4;
        FragU B1; B1.d[0] = bp(viL, zd0); B1.d[1] = bp(viL, zd1); B1.d[2] = 0; B1.d[3] = 0;
        f32x4 c1 = tov(c1b);
        c1 = MFMA16(A1.s, B1.s, c1, 0, 0, 0);
        u32 da0 = cvt_pk_bf16(fmaxf(c1[0], 0.f), fmaxf(c1[1], 0.f));   // features q*4+0,1
        u32 da1 = cvt_pk_bf16(fmaxf(c1[2], 0.f), fmaxf(c1[3], 0.f));   // features q*4+2,3

        // L2: B[k][n] via 4 bpermutes; k=0..15 = h1 (hi), k=16..31 = h1 again (lo)
        FragU B2;
        B2.d[0] = bp(i2a, da0); B2.d[1] = bp(i2a, da1);
        B2.d[2] = bp(i2b, da0); B2.d[3] = bp(i2b, da1);
        f32x4 ca = tov(c2b0), cb = tov(c2b1);
        ca = MFMA16(A2a.s, B2.s, ca, 0, 0, 0);
        cb = MFMA16(A2b.s, B2.s, cb, 0, 0, 0);
        u32 ea0 = cvt_pk_bf16(fmaxf(ca[0],0.f), fmaxf(ca[1],0.f));   // features  q*4+0,1
        u32 ea1 = cvt_pk_bf16(fmaxf(ca[2],0.f), fmaxf(ca[3],0.f));
        u32 eb0 = cvt_pk_bf16(fmaxf(cb[0],0.f), fmaxf(cb[1],0.f));   // features 16+q*4+..
        u32 eb1 = cvt_pk_bf16(fmaxf(cb[2],0.f), fmaxf(cb[3],0.f));

        // L3: B over 32 features; tile-select (q<2 -> features<16) after
        // full-exec bpermutes (no divergent cross-lane ops)
        u32 s0a = bp(i2a, ea0), s0b = bp(i2a, eb0);
        u32 s1a = bp(i2a, ea1), s1b = bp(i2a, eb1);
        u32 s2_ = bp(i2b, ea0), s2b = bp(i2b, eb0);
        u32 s3a = bp(i2b, ea1), s3b = bp(i2b, eb1);
        FragU B3;
        B3.d[0] = qlt2 ? s0a : s0b;
        B3.d[1] = qlt2 ? s1a : s1b;
        B3.d[2] = qlt2 ? s2_ : s2b;
        B3.d[3] = qlt2 ? s3a : s3b;
        f32x4 c3 = tov(c3b);
        c3 = MFMA16(A3l.s, B3.s, c3, 0, 0, 0);
        c3 = MFMA16(A3h.s, B3.s, c3, 0, 0, 0);

        // store: row = batch (col n), features q*4..q*4+3 -> contiguous 16B
        int R = gbase + t * 16 + vn;
        if (R < n)
            *reinterpret_cast<float4*>(out + (size_t)R * 16 + vq * 4) =
                make_float4(c3[0], c3[1], c3[2], c3[3]);
    }
}

extern "C" void kernel_launch(void* const* d_in, const int* in_sizes, int n_in,
                              void* d_out, int out_size, void* d_ws, size_t ws_size,
                              hipStream_t stream) {
    const float* x  = (const float*)d_in[0];
    const float* qw = (const float*)d_in[1];
    const float* W1 = (const float*)d_in[2];
    const float* b1 = (const float*)d_in[3];
    const float* W2 = (const float*)d_in[4];
    const float* b2 = (const float*)d_in[5];
    const float* W3 = (const float*)d_in[6];
    const float* b3 = (const float*)d_in[7];
    float* out = (float*)d_out;

    int n = in_sizes[0] / 16;             // B
    int blocks = (n + 255) / 256;
    qae_bperm<<<blocks, 256, 0, stream>>>(x, qw, W1, b1, W2, b2, W3, b3, out, n);
}